// Round 7
// baseline (146.229 us; speedup 1.0000x reference)
//
#include <hip/hip_runtime.h>
#include <math.h>

#define HWSZ 4096   // 64*64
// 1/sqrt(32) * log2(e): scores come out pre-multiplied by log2(e), so softmax
// uses p = exp2(S) (single v_exp_f32) -- mathematically identical.
#define QSCALE_L2E 0.25501988932587245f

typedef __bf16 bf16x2 __attribute__((ext_vector_type(2)));
typedef __bf16 bf16x4 __attribute__((ext_vector_type(4)));
typedef __bf16 bf16x8 __attribute__((ext_vector_type(8)));
typedef float  f32x4  __attribute__((ext_vector_type(4)));

// K_pad: [b][68][68][256] token-major padded K (halo = K-bias vector)
// V_padT: [b][256][68][68] dim-major padded V (halo = V-bias value)
#define KPAD_B 1183744   // 68*68*256
#define VROW   4624      // 68*68

// ================= stage 1 fused =================
// blocks 0-511:   LayerNorm strip + fused pools + Fbt bf16 token-major copy
// blocks 512-575: weight transposes (qkv_w -> WT, out_w -> WoT)
// blocks 576-607: K_pad bias fill  (interior overwritten by kv_pix GEMM)
// blocks 608-623: V_padT bias fill
__global__ __launch_bounds__(256) void fused_pre(
    const float* __restrict__ F, const float* __restrict__ lnw,
    const float* __restrict__ lnb, __bf16* __restrict__ qnb,
    float* __restrict__ mid, float* __restrict__ glb,
    const float* __restrict__ Wqkv, const float* __restrict__ Wout,
    __bf16* __restrict__ WT, __bf16* __restrict__ WoT,
    const float* __restrict__ qkvb,
    __bf16* __restrict__ Kpad, __bf16* __restrict__ VpadT,
    __bf16* __restrict__ Fbt)
{
  __shared__ float sbuf[64*68];        // union: ln needs 16*269=4304f, wtrans 64*68=4352f
  int u = blockIdx.x;
  int tid = threadIdx.x;
  if (u < 512) {
    // ---------------- LayerNorm + pools + Fbt ----------------
    float* sm = sbuf;                  // [c16] stride 269, [py] stride 67, [x]
    int blk = u;                       // b*256 + wy*16 + t
    int b = blk >> 8, wy = (blk >> 4) & 15, t = blk & 15;
    const float* Fb = F + ((size_t)(b*256 + t*16))*HWSZ + (wy*4)*64;
    int py = tid >> 6, x = tid & 63;
    #pragma unroll
    for (int j = 0; j < 16; ++j)
      sm[j*269 + py*67 + x] = Fb[(size_t)j*HWSZ + py*64 + x];
    __syncthreads();

    // Fbt: bf16 token-major copy of the raw strip (thread = one pixel, 16 ch)
    {
      __bf16* fd = Fbt + (((size_t)b*HWSZ) + (size_t)(wy*4+py)*64 + x)*256 + t*16;
      bf16x8 f0, f1;
      #pragma unroll
      for (int j = 0; j < 8; ++j) {
        f0[j] = (__bf16)sm[j*269     + py*67 + x];
        f1[j] = (__bf16)sm[(j+8)*269 + py*67 + x];
      }
      *(bf16x8*)fd = f0; *(bf16x8*)(fd + 8) = f1;
    }

    // pools from the staged RAW strip
    {
      int j = tid >> 4, u16 = tid & 15;
      const float* r0 = &sm[j*269];            // py stride 67
      int xb = u16*4;
      float m00 = 0.25f*(r0[xb]      + r0[xb+1]    + r0[67+xb]   + r0[67+xb+1]);
      float m01 = 0.25f*(r0[xb+2]    + r0[xb+3]    + r0[67+xb+2] + r0[67+xb+3]);
      float m10 = 0.25f*(r0[134+xb]  + r0[134+xb+1]+ r0[201+xb]  + r0[201+xb+1]);
      float m11 = 0.25f*(r0[134+xb+2]+ r0[134+xb+3]+ r0[201+xb+2]+ r0[201+xb+3]);
      int c = t*16 + j;
      float* mp = mid + ((size_t)(b*256 + c))*1024 + (wy*2)*32 + u16*2;
      *(float2*)mp        = make_float2(m00, m01);
      *(float2*)(mp + 32) = make_float2(m10, m11);
      glb[((size_t)(b*256 + c))*256 + wy*16 + u16] = 0.25f*(m00 + m01 + m10 + m11);
    }

    int wx = tid >> 4, cl = tid & 15;  // window wx, channel-lane cl
    float vals[16], s1 = 0.f, s2 = 0.f;
    #pragma unroll
    for (int p = 0; p < 16; ++p) {
      float v = sm[cl*269 + (p >> 2)*67 + wx*4 + (p & 3)];
      vals[p] = v; s1 += v; s2 += v*v;
    }
    #pragma unroll
    for (int m = 1; m < 16; m <<= 1) { s1 += __shfl_xor(s1, m); s2 += __shfl_xor(s2, m); }
    float mean = s1 * (1.f/256.f);
    float var  = s2 * (1.f/256.f) - mean*mean;
    float rstd = rsqrtf(var + 1e-5f);
    __bf16* outp = qnb + (((size_t)(b*256 + wy*16 + wx))*16 + t)*256 + cl*16;
    bf16x8 o0, o1;
    #pragma unroll
    for (int p = 0; p < 8; ++p) {
      o0[p] = (__bf16)((vals[p]  -mean)*rstd*lnw[cl*16+p]   + lnb[cl*16+p]);
      o1[p] = (__bf16)((vals[p+8]-mean)*rstd*lnw[cl*16+p+8] + lnb[cl*16+p+8]);
    }
    *(bf16x8*)outp = o0;
    *(bf16x8*)(outp+8) = o1;
  } else if (u < 576) {
    // ---------------- weight transposes ----------------
    float (*T)[68] = (float(*)[68])sbuf;
    int v = u - 512;                   // 0..63: bx = v&15, k-block = v>>4
    int bx = v & 15, k0 = (v >> 4)*64;
    int c4 = (tid & 15)*4, rr = tid >> 4;
    const float* W; __bf16* D; int ncols, n0;
    if (bx < 12) { W = Wqkv; D = WT;  ncols = 768; n0 = bx*64; }
    else         { W = Wout; D = WoT; ncols = 256; n0 = (bx-12)*64; }
    #pragma unroll
    for (int p = 0; p < 4; ++p) {
      int row = p*16 + rr;
      float4 vv = *(const float4*)(W + (size_t)(k0+row)*ncols + n0 + c4);
      T[c4+0][row] = vv.x; T[c4+1][row] = vv.y; T[c4+2][row] = vv.z; T[c4+3][row] = vv.w;
    }
    __syncthreads();
    #pragma unroll
    for (int p = 0; p < 4; ++p) {
      int cc = p*16 + rr;
      bf16x4 o;
      o[0] = (__bf16)T[cc][c4+0]; o[1] = (__bf16)T[cc][c4+1];
      o[2] = (__bf16)T[cc][c4+2]; o[3] = (__bf16)T[cc][c4+3];
      *(bf16x4*)(D + (size_t)(n0+cc)*256 + k0 + c4) = o;
    }
  } else if (u < 608) {
    // ---------------- K_pad bias fill ----------------
    int gid = (u - 576)*256 + tid;     // 0..8191
    int nv = gid & 31;                 // fixed vec8 slot within 256 dims
    bf16x8 kv;
    #pragma unroll
    for (int j = 0; j < 8; ++j) kv[j] = (__bf16)qkvb[256 + nv*8 + j];
    for (int pos = gid >> 5; pos < 9248; pos += 256)
      *(bf16x8*)(Kpad + (size_t)pos*256 + nv*8) = kv;
  } else {
    // ---------------- V_padT bias fill ----------------
    int gid = (u - 608)*256 + tid;     // 0..4095
    int row = gid >> 3, sub = gid & 7; // row = b*256 + dim, 8 threads/row
    __bf16 vvs = (__bf16)qkvb[512 + (row & 255)];
    bf16x8 vv;
    #pragma unroll
    for (int j = 0; j < 8; ++j) vv[j] = vvs;
    __bf16* dst = VpadT + (size_t)row*VROW;
    for (int s = sub; s < 578; s += 8)
      *(bf16x8*)(dst + s*8) = vv;
  }
}

// ================= stage 2 fused: the three projection GEMMs =================
// BARRIER-FREE version: B-fragments are loaded per-lane straight from WT
// (L2-broadcast, 64B-line coalesced across the wave) -- no LDS staging, no
// __syncthreads anywhere. Blocks are pure streaming; latency hidden by TLP.
// blocks 0-511:   kv_pix  (per-pixel K/V into padded arrays)
// blocks 512-767: q GEMM
// blocks 768-927: mid/glb KV
__global__ __launch_bounds__(256) void fused_gemms(
    const __bf16* __restrict__ Fbt, const __bf16* __restrict__ qnb,
    const float* __restrict__ mid, const float* __restrict__ glb,
    const __bf16* __restrict__ WT, const float* __restrict__ qkvb,
    __bf16* __restrict__ qbf, __bf16* __restrict__ Kpad,
    __bf16* __restrict__ VpadT, __bf16* __restrict__ kmg,
    __bf16* __restrict__ vmgt)
{
  int u = blockIdx.x;
  int tid = threadIdx.x;
  int wv = tid >> 6, lane = tid & 63;
  int col = lane & 15, quad = lane >> 4;
  const f32x4 zero = {0.f,0.f,0.f,0.f};

  if (u < 512) {
    // ---------------- kv_pix ----------------
    int mb = u >> 2, ns = u & 3;       // mb: b*64 + y ; ns: N-split
    int b = mb >> 6, y = mb & 63;
    int x0w = wv*16;                   // wave's x-offset within the row

    // A-frags: contiguous bf16x8 loads from the token-major copy
    bf16x8 af[8];
    const __bf16* Fp = Fbt + (((size_t)b*HWSZ) + y*64 + x0w + col)*256 + quad*8;
    #pragma unroll
    for (int kk = 0; kk < 8; ++kk) af[kk] = *(const bf16x8*)(Fp + kk*32);

    // per-lane B-frag base: row (256+ns*128+nt*16+col) of WT, seg quad*8
    const __bf16* wb = WT + ((size_t)(256 + ns*128 + col))*256 + quad*8;
    bool isK = (ns < 2);
    #pragma unroll 2
    for (int nt = 0; nt < 8; ++nt) {
      const __bf16* Bb = wb + (size_t)nt*16*256;
      f32x4 acc = zero;
      if (isK) {
        #pragma unroll
        for (int kk = 0; kk < 8; ++kk) {
          bf16x8 bv = *(const bf16x8*)(Bb + kk*32);
          acc = __builtin_amdgcn_mfma_f32_16x16x32_bf16(af[kk], bv, acc, 0, 0, 0);
        }
        int n = ns*128 + nt*16 + col;
        float bias_n = qkvb[256 + n];
        #pragma unroll
        for (int r = 0; r < 4; ++r) {
          int x = x0w + quad*4 + r;
          Kpad[(size_t)b*KPAD_B + ((size_t)(y+2)*68 + (x+2))*256 + n]
              = (__bf16)(acc[r] + bias_n);
        }
      } else {
        #pragma unroll
        for (int kk = 0; kk < 8; ++kk) {
          bf16x8 bv = *(const bf16x8*)(Bb + kk*32);
          acc = __builtin_amdgcn_mfma_f32_16x16x32_bf16(bv, af[kk], acc, 0, 0, 0);
        }
        int x = x0w + col;
        #pragma unroll
        for (int r = 0; r < 4; ++r) {
          int dim = (ns - 2)*128 + nt*16 + quad*4 + r;
          float bias_d = qkvb[512 + dim];
          VpadT[((size_t)(b*256 + dim))*VROW + (size_t)(y+2)*68 + (x+2)]
              = (__bf16)(acc[r] + bias_d);
        }
      }
    }
  } else if (u < 768) {
    // ---------------- q GEMM ----------------
    int blk = u - 512;                 // tb*2 + nh
    int tb = blk >> 1, nh = blk & 1;
    int n0 = nh*128;
    int m0 = tb*64 + wv*16;

    bf16x8 bq[8];
    const __bf16* qp = qnb + ((size_t)(m0 + col))*256 + quad*8;
    #pragma unroll
    for (int kk = 0; kk < 8; ++kk) bq[kk] = *(const bf16x8*)(qp + kk*32);

    const __bf16* wb = WT + ((size_t)(n0 + col))*256 + quad*8;
    #pragma unroll 2
    for (int s = 0; s < 8; ++s) {
      const __bf16* Ab = wb + (size_t)s*16*256;
      f32x4 acc = zero;
      #pragma unroll
      for (int kk = 0; kk < 8; ++kk) {
        bf16x8 wf = *(const bf16x8*)(Ab + kk*32);
        acc = __builtin_amdgcn_mfma_f32_16x16x32_bf16(wf, bq[kk], acc, 0, 0, 0);
      }
      int nq4 = n0 + s*16 + quad*4;
      float4 b4 = *(const float4*)(qkvb + nq4);
      float bb[4] = {b4.x, b4.y, b4.z, b4.w};
      bf16x4 o;
      #pragma unroll
      for (int r = 0; r < 4; ++r) o[r] = (__bf16)((acc[r]+bb[r])*QSCALE_L2E);
      *(bf16x4*)(qbf + ((size_t)(m0 + col))*256 + nq4) = o;
    }
  } else {
    // ---------------- mid/glb KV: direct f32 A-frags ----------------
    int v = u - 768;                   // 0..159: (tb 20, nq 4, b 2)
    int tb = v % 20, nq = (v / 20) & 3, b = v / 80;
    int m0 = tb*64 + wv*16;
    int n0 = nq*128;

    bf16x8 af[8];
    if (tb < 16) {
      const float* Abase = mid + ((size_t)(b*256))*1024 + (m0 + col);
      #pragma unroll
      for (int kk = 0; kk < 8; ++kk) {
        #pragma unroll
        for (int j = 0; j < 8; ++j)
          af[kk][j] = (__bf16)Abase[(size_t)(kk*32 + quad*8 + j)*1024];
      }
    } else {
      const float* Abase = glb + ((size_t)(b*256))*256 + (m0 - 1024 + col);
      #pragma unroll
      for (int kk = 0; kk < 8; ++kk) {
        #pragma unroll
        for (int j = 0; j < 8; ++j)
          af[kk][j] = (__bf16)Abase[(size_t)(kk*32 + quad*8 + j)*256];
      }
    }

    const __bf16* wb = WT + ((size_t)(256 + n0 + col))*256 + quad*8;
    #pragma unroll 2
    for (int s = 0; s < 8; ++s) {
      const __bf16* Bb = wb + (size_t)s*16*256;
      int n = n0 + s*16 + col;
      float bias_n = qkvb[256 + n];
      f32x4 acc = zero;
      #pragma unroll
      for (int kk = 0; kk < 8; ++kk) {
        bf16x8 bv = *(const bf16x8*)(Bb + kk*32);
        acc = __builtin_amdgcn_mfma_f32_16x16x32_bf16(af[kk], bv, acc, 0, 0, 0);
      }
      if (n < 256) {
        #pragma unroll
        for (int r = 0; r < 4; ++r)
          kmg[((size_t)b*1280 + m0 + quad*4 + r)*256 + n] = (__bf16)(acc[r] + bias_n);
      } else {
        bf16x4 o;
        #pragma unroll
        for (int r = 0; r < 4; ++r) o[r] = (__bf16)(acc[r] + bias_n);
        *(bf16x4*)(vmgt + ((size_t)b*256 + (n - 256))*1280 + m0 + quad*4) = o;
      }
    }
  }
}

// ---------------- MFMA fused attention: 128-token slabs (10 barriers) ----------------
__global__ __launch_bounds__(512) void attn_mfma(
    const __bf16* __restrict__ qbf, const __bf16* __restrict__ Kpad,
    const __bf16* __restrict__ VpadT, const __bf16* __restrict__ kmg,
    const __bf16* __restrict__ vmgt, __bf16* __restrict__ obf)
{
  __shared__ __bf16 Ks[2][128][40];     // 20.5 KB: 128 token rows x 32 dims (+pad)
  __shared__ __bf16 Vs[2][32][136];     // 17.4 KB: 32 dim rows x 128 tokens (+pad)
  int blk = blockIdx.x;
  int b = blk >> 8, rr = blk & 255;
  int h = rr >> 5, wg = rr & 31;
  int tid = threadIdx.x, wv = tid >> 6, lane = tid & 63;
  int col = lane & 15, quad = lane >> 4;
  int w = wg*8 + wv;                    // this wave's window (within batch)
  int bw = b*256 + w;

  // slab staging: each thread stages TWO 16B pieces per 128-token slab
  bool isK = tid < 256;
  int krow = tid >> 2,        kseg = tid & 3;          // 64 rows x 4 segs
  int vrow = (tid - 256) >> 3, vseg = (tid - 256) & 7; // 32 rows x 8 segs
  const __bf16* gbase;
  __bf16 *d0a, *d0b, *d1a, *d1b;
  size_t gslab, soff2;
  if (isK) {
    gbase = kmg + ((size_t)(b*1280 + krow))*256 + h*32 + kseg*8;
    gslab = (size_t)128*256;
    soff2 = (size_t)64*256;             // second piece: token krow+64
    d0a = &Ks[0][krow][kseg*8];    d0b = &Ks[0][64+krow][kseg*8];
    d1a = &Ks[1][krow][kseg*8];    d1b = &Ks[1][64+krow][kseg*8];
  } else {
    gbase = vmgt + ((size_t)(b*256 + h*32 + vrow))*1280 + vseg*8;
    gslab = 128;
    soff2 = 64;                         // second piece: tokens +64
    d0a = &Vs[0][vrow][vseg*8];    d0b = &Vs[0][vrow][64+vseg*8];
    d1a = &Vs[1][vrow][vseg*8];    d1b = &Vs[1][vrow][64+vseg*8];
  }

  bf16x8 aq = *(const bf16x8*)(qbf + ((size_t)(bw*16 + col))*256 + h*32 + quad*8);
  f32x4 O0 = {0.f,0.f,0.f,0.f}, O1 = {0.f,0.f,0.f,0.f};
  const f32x4 zero = {0.f,0.f,0.f,0.f};
  float ls = 0.f;                       // row-sum for q=col (this lane's 8 k-slots)

  // issue slab-0 loads early
  bf16x8 sa = *(const bf16x8*)gbase;
  bf16x8 sb = *(const bf16x8*)(gbase + soff2);

  // ---- local chunks 0,1: padded-pixel gathers ----
  int wy = w >> 4, wx = w & 15;
  int py = wy*4, px = wx*4;             // padded top-left of the 8x8 patch
  const __bf16* kb = Kpad + (size_t)b*KPAD_B + h*32 + quad*8;
  int kr = (py + (col >> 3))*68 + px + (col & 7);
  const __bf16* vp0 = VpadT + ((size_t)(b*256 + h*32 + col))*VROW;
  const __bf16* vp1 = vp0 + (size_t)16*VROW;
  int vr = (py + (quad >> 1))*68 + px + (quad & 1)*4;
  #pragma unroll
  for (int ch = 0; ch < 2; ++ch) {
    int ko = kr + ch*272;               // +ch*4 rows
    bf16x8 k0 = *(const bf16x8*)(kb + (size_t)ko*256);
    bf16x8 k1 = *(const bf16x8*)(kb + (size_t)(ko + 136)*256);   // +2 rows (=+16 tokens)
    int vo = vr + ch*272;
    bf16x4 va0 = *(const bf16x4*)(vp0 + vo);
    bf16x4 va1 = *(const bf16x4*)(vp0 + vo + 136);
    bf16x4 vb0 = *(const bf16x4*)(vp1 + vo);
    bf16x4 vb1 = *(const bf16x4*)(vp1 + vo + 136);
    f32x4 S0 = __builtin_amdgcn_mfma_f32_16x16x32_bf16(k0, aq, zero, 0, 0, 0);
    f32x4 S1 = __builtin_amdgcn_mfma_f32_16x16x32_bf16(k1, aq, zero, 0, 0, 0);
    bf16x8 pf;
    #pragma unroll
    for (int r = 0; r < 4; ++r) {
      float p0 = __builtin_amdgcn_exp2f(S0[r]);
      float p1 = __builtin_amdgcn_exp2f(S1[r]);
      ls += p0 + p1;
      pf[r] = (__bf16)p0; pf[4+r] = (__bf16)p1;
    }
    bf16x8 v0 = __builtin_shufflevector(va0, va1, 0,1,2,3,4,5,6,7);
    bf16x8 v1 = __builtin_shufflevector(vb0, vb1, 0,1,2,3,4,5,6,7);
    O0 = __builtin_amdgcn_mfma_f32_16x16x32_bf16(pf, v0, O0, 0, 0, 0);
    O1 = __builtin_amdgcn_mfma_f32_16x16x32_bf16(pf, v1, O1, 0, 0, 0);
  }

  // write slab 0 to buf0, prefetch slab 1
  *(bf16x8*)d0a = sa; *(bf16x8*)d0b = sb;
  sa = *(const bf16x8*)(gbase + gslab);
  sb = *(const bf16x8*)(gbase + gslab + soff2);
  __syncthreads();

  #pragma unroll 1
  for (int s = 0; s < 10; ++s) {
    if (s + 1 < 10) {
      if (s & 1) { *(bf16x8*)d0a = sa; *(bf16x8*)d0b = sb; }
      else       { *(bf16x8*)d1a = sa; *(bf16x8*)d1b = sb; }
      if (s + 2 < 10) {
        sa = *(const bf16x8*)(gbase + (size_t)(s+2)*gslab);
        sb = *(const bf16x8*)(gbase + (size_t)(s+2)*gslab + soff2);
      }
    }
    const __bf16* Kb = &Ks[s & 1][0][0];
    const __bf16* Vb = &Vs[s & 1][0][0];
    #pragma unroll
    for (int c = 0; c < 4; ++c) {
      bf16x8 k0 = *(const bf16x8*)(Kb + (c*32 + col)*40 + quad*8);
      bf16x8 k1 = *(const bf16x8*)(Kb + (c*32 + 16 + col)*40 + quad*8);
      bf16x4 va0 = *(const bf16x4*)(Vb + (size_t)col*136      + c*32 + quad*4);
      bf16x4 va1 = *(const bf16x4*)(Vb + (size_t)col*136      + c*32 + 16 + quad*4);
      bf16x4 vb0 = *(const bf16x4*)(Vb + (size_t)(16+col)*136 + c*32 + quad*4);
      bf16x4 vb1 = *(const bf16x4*)(Vb + (size_t)(16+col)*136 + c*32 + 16 + quad*4);
      f32x4 S0 = __builtin_amdgcn_mfma_f32_16x16x32_bf16(k0, aq, zero, 0, 0, 0);
      f32x4 S1 = __builtin_amdgcn_mfma_f32_16x16x32_bf16(k1, aq, zero, 0, 0, 0);
      bf16x8 pf;
      #pragma unroll
      for (int r = 0; r < 4; ++r) {
        float p0 = __builtin_amdgcn_exp2f(S0[r]);
        float p1 = __builtin_amdgcn_exp2f(S1[r]);
        ls += p0 + p1;
        pf[r] = (__bf16)p0; pf[4+r] = (__bf16)p1;
      }
      bf16x8 v0 = __builtin_shufflevector(va0, va1, 0,1,2,3,4,5,6,7);
      bf16x8 v1 = __builtin_shufflevector(vb0, vb1, 0,1,2,3,4,5,6,7);
      O0 = __builtin_amdgcn_mfma_f32_16x16x32_bf16(pf, v0, O0, 0, 0, 0);
      O1 = __builtin_amdgcn_mfma_f32_16x16x32_bf16(pf, v1, O1, 0, 0, 0);
    }
    __syncthreads();
  }

  // lanes (col, quad=0..3) partition the k-range of row q=col: reduce over quads
  ls += __shfl_xor(ls, 16);
  ls += __shfl_xor(ls, 32);
  // O0[r] is q=quad*4+r: fetch L[q] from lane (col'=q, quad'=0)
  __bf16* op = obf + ((size_t)(bw*16) + quad*4)*256 + h*32 + col;
  #pragma unroll
  for (int r = 0; r < 4; ++r) {
    float inv = 1.f / __shfl(ls, quad*4 + r);
    op[(size_t)r*256]      = (__bf16)(O0[r]*inv);
    op[(size_t)r*256 + 16] = (__bf16)(O1[r]*inv);
  }
}

// ---------------- out projection v3: 256 blocks (each handles 8 wx) ----------------
__global__ __launch_bounds__(256) void gemm_out_strip(
    const __bf16* __restrict__ obf, const __bf16* __restrict__ WoT,
    const float* __restrict__ outb, const float* __restrict__ Fres,
    float* __restrict__ Out)
{
  __shared__ __bf16 Bs4[4*16*264];     // 33 KB: this block's 4 WoT tiles
  __shared__ __bf16 strip[64*264];     // 33 KB (half used per block)
  int blk = blockIdx.x;                // b*128 + wy*8 + cq*2 + xh
  int b = blk >> 7, rest = blk & 127;
  int wy = rest >> 3, cq = (rest >> 1) & 3, xh = rest & 1;
  int c0 = cq*64;
  int tid = threadIdx.x, wv = tid >> 6, lane = tid & 63;
  int col = lane & 15, quad = lane >> 4;
  const f32x4 zero = {0.f,0.f,0.f,0.f};

  {
    int brow = tid >> 4, bseg = tid & 15;
    const __bf16* wsrc = WoT + ((size_t)(c0 + brow))*256 + bseg*16;
    #pragma unroll
    for (int s = 0; s < 4; ++s) {
      bf16x8 a0 = *(const bf16x8*)(wsrc + (size_t)s*4096);
      bf16x8 a1 = *(const bf16x8*)(wsrc + (size_t)s*4096 + 8);
      __bf16* d = Bs4 + s*4224 + brow*264 + bseg*16;
      *(bf16x8*)d = a0; *(bf16x8*)(d + 8) = a1;
    }
  }
  __syncthreads();

  #pragma unroll
  for (int i = 0; i < 2; ++i) {
    int wx = xh*8 + wv*2 + i;
    int win = b*256 + wy*16 + wx;
    bf16x8 ao[8];
    const __bf16* op = obf + ((size_t)win*16 + col)*256 + quad*8;
    #pragma unroll
    for (int kk = 0; kk < 8; ++kk) ao[kk] = *(const bf16x8*)(op + kk*32);
    #pragma unroll
    for (int nt = 0; nt < 4; ++nt) {
      const __bf16* Bb = Bs4 + nt*4224 + col*264 + quad*8;
      f32x4 acc = zero;
      #pragma unroll
      for (int kk = 0; kk < 8; ++kk) {
        bf16x8 wf = *(const bf16x8*)(Bb + kk*32);
        acc = __builtin_amdgcn_mfma_f32_16x16x32_bf16(ao[kk], wf, acc, 0, 0, 0);
      }
      bf16x4 o;
      #pragma unroll
      for (int r = 0; r < 4; ++r) o[r] = (__bf16)acc[r];
      *(bf16x4*)&strip[(nt*16+col)*264 + quad*66 + wx*4] = o;
    }
  }
  __syncthreads();
  #pragma unroll
  for (int j = 0; j < 8; ++j) {
    int f4 = j*256 + tid;               // 2048 = 64c x 4y x 8xq
    int xq = (f4 & 7) + xh*8, y = (f4 >> 3) & 3, c = f4 >> 5;
    bf16x4 d = *(const bf16x4*)&strip[c*264 + y*66 + xq*4];
    size_t off = ((size_t)(b*256 + c0 + c))*HWSZ + (wy*4 + y)*64 + xq*4;
    float4 r4 = *(const float4*)(Fres + off);
    float bn = outb[c0 + c];
    float4 o;
    o.x = (float)d[0] + bn + r4.x; o.y = (float)d[1] + bn + r4.y;
    o.z = (float)d[2] + bn + r4.z; o.w = (float)d[3] + bn + r4.w;
    *(float4*)(Out + off) = o;
  }
}

extern "C" void kernel_launch(void* const* d_in, const int* in_sizes, int n_in,
                              void* d_out, int out_size, void* d_ws, size_t ws_size,
                              hipStream_t stream) {
  const float* F     = (const float*)d_in[0];
  const float* qkv_w = (const float*)d_in[1];
  const float* qkv_b = (const float*)d_in[2];
  const float* out_w = (const float*)d_in[3];
  const float* out_b = (const float*)d_in[4];
  const float* ln_w  = (const float*)d_in[5];
  const float* ln_b  = (const float*)d_in[6];
  float* out = (float*)d_out;

  __bf16* qnb   = (__bf16*)d_ws;             // 2,097,152 h
  __bf16* qbf   = qnb   + 2097152;           // 2,097,152 h
  __bf16* obf   = qbf   + 2097152;           // 2,097,152 h
  __bf16* Kpad  = obf   + 2097152;           // 2,367,488 h (2*68*68*256)
  __bf16* VpadT = Kpad  + 2367488;           // 2,367,488 h
  __bf16* kmg   = VpadT + 2367488;           // 655,360 h
  __bf16* vmgt  = kmg   + 655360;            // 655,360 h
  __bf16* Fbt   = vmgt  + 655360;            // 2,097,152 h (bf16 token-major F)
  __bf16* WT    = Fbt   + 2097152;           // 196,608 h
  __bf16* WoT   = WT    + 196608;            // 65,536 h
  float*  mid   = (float*)(WoT + 65536);     // 524,288 f
  float*  glb   = mid   + 524288;            // 131,072 f

  fused_pre<<<624, 256, 0, stream>>>(F, ln_w, ln_b, qnb, mid, glb,
                                     qkv_w, out_w, WT, WoT, qkv_b,
                                     Kpad, VpadT, Fbt);
  fused_gemms<<<928, 256, 0, stream>>>(Fbt, qnb, mid, glb, WT, qkv_b,
                                       qbf, Kpad, VpadT, kmg, vmgt);
  attn_mfma<<<512, 512, 0, stream>>>(qbf, Kpad, VpadT, kmg, vmgt, obf);
  gemm_out_strip<<<256, 256, 0, stream>>>(obf, WoT, out_b, F, out);
}

// Round 8
// 123.420 us; speedup vs baseline: 1.1848x; 1.1848x over previous
//
#include <hip/hip_runtime.h>
#include <math.h>

#define HWSZ 4096   // 64*64
// 1/sqrt(32) * log2(e): scores come out pre-multiplied by log2(e), so softmax
// uses p = exp2(S) (single v_exp_f32) -- mathematically identical.
#define QSCALE_L2E 0.25501988932587245f

typedef __bf16 bf16x2 __attribute__((ext_vector_type(2)));
typedef __bf16 bf16x4 __attribute__((ext_vector_type(4)));
typedef __bf16 bf16x8 __attribute__((ext_vector_type(8)));
typedef float  f32x4  __attribute__((ext_vector_type(4)));

// K_pad: [b][68][68][256] token-major padded K (halo = K-bias vector)
// V_padT: [b][256][68][68] dim-major padded V (halo = V-bias value)
#define KPAD_B 1183744   // 68*68*256
#define VROW   4624      // 68*68

// ================= stage 1 fused =================
// blocks 0-511:   LayerNorm strip + fused pools (pool reads the raw F strip
//                 already staged in LDS)
// blocks 512-575: weight transposes (qkv_w -> WT, out_w -> WoT)
// blocks 576-607: K_pad bias fill  (interior overwritten by kv_pix GEMM)
// blocks 608-623: V_padT bias fill
__global__ __launch_bounds__(256) void fused_pre(
    const float* __restrict__ F, const float* __restrict__ lnw,
    const float* __restrict__ lnb, __bf16* __restrict__ qnb,
    float* __restrict__ mid, float* __restrict__ glb,
    const float* __restrict__ Wqkv, const float* __restrict__ Wout,
    __bf16* __restrict__ WT, __bf16* __restrict__ WoT,
    const float* __restrict__ qkvb,
    __bf16* __restrict__ Kpad, __bf16* __restrict__ VpadT)
{
  __shared__ float sbuf[64*68];        // union: ln needs 16*269=4304f, wtrans 64*68=4352f
  int u = blockIdx.x;
  int tid = threadIdx.x;
  if (u < 512) {
    // ---------------- LayerNorm + pools ----------------
    float* sm = sbuf;                  // [c16] stride 269, [py] stride 67, [x]
    int blk = u;                       // b*256 + wy*16 + t
    int b = blk >> 8, wy = (blk >> 4) & 15, t = blk & 15;
    const float* Fb = F + ((size_t)(b*256 + t*16))*HWSZ + (wy*4)*64;
    int py = tid >> 6, x = tid & 63;
    #pragma unroll
    for (int j = 0; j < 16; ++j)
      sm[j*269 + py*67 + x] = Fb[(size_t)j*HWSZ + py*64 + x];
    __syncthreads();

    // pools from the staged RAW strip: this block owns mid rows wy*2,wy*2+1
    // and glb row wy for channels t*16..t*16+15.
    {
      int j = tid >> 4, u16 = tid & 15;
      const float* r0 = &sm[j*269];            // py stride 67
      int xb = u16*4;
      float m00 = 0.25f*(r0[xb]      + r0[xb+1]    + r0[67+xb]   + r0[67+xb+1]);
      float m01 = 0.25f*(r0[xb+2]    + r0[xb+3]    + r0[67+xb+2] + r0[67+xb+3]);
      float m10 = 0.25f*(r0[134+xb]  + r0[134+xb+1]+ r0[201+xb]  + r0[201+xb+1]);
      float m11 = 0.25f*(r0[134+xb+2]+ r0[134+xb+3]+ r0[201+xb+2]+ r0[201+xb+3]);
      int c = t*16 + j;
      float* mp = mid + ((size_t)(b*256 + c))*1024 + (wy*2)*32 + u16*2;
      *(float2*)mp        = make_float2(m00, m01);
      *(float2*)(mp + 32) = make_float2(m10, m11);
      glb[((size_t)(b*256 + c))*256 + wy*16 + u16] = 0.25f*(m00 + m01 + m10 + m11);
    }

    int wx = tid >> 4, cl = tid & 15;  // window wx, channel-lane cl
    float vals[16], s1 = 0.f, s2 = 0.f;
    #pragma unroll
    for (int p = 0; p < 16; ++p) {
      float v = sm[cl*269 + (p >> 2)*67 + wx*4 + (p & 3)];
      vals[p] = v; s1 += v; s2 += v*v;
    }
    #pragma unroll
    for (int m = 1; m < 16; m <<= 1) { s1 += __shfl_xor(s1, m); s2 += __shfl_xor(s2, m); }
    float mean = s1 * (1.f/256.f);
    float var  = s2 * (1.f/256.f) - mean*mean;
    float rstd = rsqrtf(var + 1e-5f);
    __bf16* outp = qnb + (((size_t)(b*256 + wy*16 + wx))*16 + t)*256 + cl*16;
    bf16x8 o0, o1;
    #pragma unroll
    for (int p = 0; p < 8; ++p) {
      o0[p] = (__bf16)((vals[p]  -mean)*rstd*lnw[cl*16+p]   + lnb[cl*16+p]);
      o1[p] = (__bf16)((vals[p+8]-mean)*rstd*lnw[cl*16+p+8] + lnb[cl*16+p+8]);
    }
    *(bf16x8*)outp = o0;
    *(bf16x8*)(outp+8) = o1;
  } else if (u < 576) {
    // ---------------- weight transposes ----------------
    float (*T)[68] = (float(*)[68])sbuf;
    int v = u - 512;                   // 0..63: bx = v&15, k-block = v>>4
    int bx = v & 15, k0 = (v >> 4)*64;
    int c4 = (tid & 15)*4, rr = tid >> 4;
    const float* W; __bf16* D; int ncols, n0;
    if (bx < 12) { W = Wqkv; D = WT;  ncols = 768; n0 = bx*64; }
    else         { W = Wout; D = WoT; ncols = 256; n0 = (bx-12)*64; }
    #pragma unroll
    for (int p = 0; p < 4; ++p) {
      int row = p*16 + rr;
      float4 vv = *(const float4*)(W + (size_t)(k0+row)*ncols + n0 + c4);
      T[c4+0][row] = vv.x; T[c4+1][row] = vv.y; T[c4+2][row] = vv.z; T[c4+3][row] = vv.w;
    }
    __syncthreads();
    #pragma unroll
    for (int p = 0; p < 4; ++p) {
      int cc = p*16 + rr;
      bf16x4 o;
      o[0] = (__bf16)T[cc][c4+0]; o[1] = (__bf16)T[cc][c4+1];
      o[2] = (__bf16)T[cc][c4+2]; o[3] = (__bf16)T[cc][c4+3];
      *(bf16x4*)(D + (size_t)(n0+cc)*256 + k0 + c4) = o;
    }
  } else if (u < 608) {
    // ---------------- K_pad bias fill ----------------
    int gid = (u - 576)*256 + tid;     // 0..8191
    int nv = gid & 31;                 // fixed vec8 slot within 256 dims
    bf16x8 kv;
    #pragma unroll
    for (int j = 0; j < 8; ++j) kv[j] = (__bf16)qkvb[256 + nv*8 + j];
    for (int pos = gid >> 5; pos < 9248; pos += 256)
      *(bf16x8*)(Kpad + (size_t)pos*256 + nv*8) = kv;
  } else {
    // ---------------- V_padT bias fill ----------------
    int gid = (u - 608)*256 + tid;     // 0..4095
    int row = gid >> 3, sub = gid & 7; // row = b*256 + dim, 8 threads/row
    __bf16 vvs = (__bf16)qkvb[512 + (row & 255)];
    bf16x8 vv;
    #pragma unroll
    for (int j = 0; j < 8; ++j) vv[j] = vvs;
    __bf16* dst = VpadT + (size_t)row*VROW;
    for (int s = sub; s < 578; s += 8)
      *(bf16x8*)(dst + s*8) = vv;
  }
}

// ================= stage 2 fused: the three projection GEMMs =================
// (R4 proven version: LDS-staged B tiles, double-buffered; direct F A-loads)
// blocks 0-511:   kv_pix: per-pixel K/V projection into padded arrays.
// blocks 512-767: q GEMM (WT[0:256] LDS-staged)
// blocks 768-927: mid/glb KV (direct f32 A-frag loads)
__global__ __launch_bounds__(256) void fused_gemms(
    const float* __restrict__ F, const __bf16* __restrict__ qnb,
    const float* __restrict__ mid, const float* __restrict__ glb,
    const __bf16* __restrict__ WT, const float* __restrict__ qkvb,
    __bf16* __restrict__ qbf, __bf16* __restrict__ Kpad,
    __bf16* __restrict__ VpadT, __bf16* __restrict__ kmg,
    __bf16* __restrict__ vmgt)
{
  __shared__ __bf16 Bs[2][16*264];     // 16.5 KB, shared by all branches
  int u = blockIdx.x;
  int tid = threadIdx.x;
  int wv = tid >> 6, lane = tid & 63;
  int col = lane & 15, quad = lane >> 4;
  const f32x4 zero = {0.f,0.f,0.f,0.f};

  if (u < 512) {
    // ---------------- kv_pix ----------------
    int mb = u >> 2, ns = u & 3;       // mb: b*64 + y ; ns: N-split
    int b = mb >> 6, y = mb & 63;
    int x0w = wv*16;                   // wave's x-offset within the row

    // A-frags: af[kk][j] = F[b][kk*32+quad*8+j][y][x0w+col]  (coalesced over col)
    bf16x8 af[8];
    const float* Fb = F + ((size_t)(b*256))*HWSZ + y*64 + x0w + col;
    #pragma unroll
    for (int kk = 0; kk < 8; ++kk) {
      #pragma unroll
      for (int j = 0; j < 8; ++j)
        af[kk][j] = (__bf16)Fb[(size_t)(kk*32 + quad*8 + j)*HWSZ];
    }

    int brow = tid >> 4, bseg = tid & 15;
    const __bf16* wsrc = WT + ((size_t)(256 + ns*128 + brow))*256 + bseg*16;
    {
      bf16x8 a0 = *(const bf16x8*)wsrc;
      bf16x8 a1 = *(const bf16x8*)(wsrc + 8);
      __bf16* d = &Bs[0][0] + brow*264 + bseg*16;
      *(bf16x8*)d = a0; *(bf16x8*)(d + 8) = a1;
    }
    bf16x8 g0 = *(const bf16x8*)(wsrc + (size_t)4096);
    bf16x8 g1 = *(const bf16x8*)(wsrc + (size_t)4096 + 8);
    __syncthreads();

    bool isK = (ns < 2);
    #pragma unroll 1
    for (int nt = 0; nt < 8; ++nt) {
      if (nt < 7) {
        __bf16* d = &Bs[(nt+1) & 1][0] + brow*264 + bseg*16;
        *(bf16x8*)d = g0; *(bf16x8*)(d + 8) = g1;
      }
      if (nt < 6) {
        const __bf16* p = wsrc + (size_t)(nt+2)*4096;
        g0 = *(const bf16x8*)p; g1 = *(const bf16x8*)(p + 8);
      }
      const __bf16* Bb = &Bs[nt & 1][0] + col*264 + quad*8;
      f32x4 acc = zero;
      if (isK) {
        #pragma unroll
        for (int kk = 0; kk < 8; ++kk) {
          bf16x8 bv = *(const bf16x8*)(Bb + kk*32);
          acc = __builtin_amdgcn_mfma_f32_16x16x32_bf16(af[kk], bv, acc, 0, 0, 0);
        }
        int n = ns*128 + nt*16 + col;
        float bias_n = qkvb[256 + n];
        #pragma unroll
        for (int r = 0; r < 4; ++r) {
          int x = x0w + quad*4 + r;
          Kpad[(size_t)b*KPAD_B + ((size_t)(y+2)*68 + (x+2))*256 + n]
              = (__bf16)(acc[r] + bias_n);
        }
      } else {
        #pragma unroll
        for (int kk = 0; kk < 8; ++kk) {
          bf16x8 bv = *(const bf16x8*)(Bb + kk*32);
          acc = __builtin_amdgcn_mfma_f32_16x16x32_bf16(bv, af[kk], acc, 0, 0, 0);
        }
        int x = x0w + col;
        #pragma unroll
        for (int r = 0; r < 4; ++r) {
          int dim = (ns - 2)*128 + nt*16 + quad*4 + r;
          float bias_d = qkvb[512 + dim];
          VpadT[((size_t)(b*256 + dim))*VROW + (size_t)(y+2)*68 + (x+2)]
              = (__bf16)(acc[r] + bias_d);
        }
      }
      __syncthreads();
    }
  } else if (u < 768) {
    // ---------------- q GEMM ----------------
    int blk = u - 512;                 // tb*2 + nh
    int tb = blk >> 1, nh = blk & 1;
    int n0 = nh*128;
    int m0 = tb*64 + wv*16;

    bf16x8 bq[8];
    const __bf16* qp = qnb + ((size_t)(m0 + col))*256 + quad*8;
    #pragma unroll
    for (int kk = 0; kk < 8; ++kk) bq[kk] = *(const bf16x8*)(qp + kk*32);

    int brow = tid >> 4, bseg = tid & 15;
    const __bf16* wsrc = WT + ((size_t)(n0 + brow))*256 + bseg*16;
    {
      bf16x8 a0 = *(const bf16x8*)wsrc;
      bf16x8 a1 = *(const bf16x8*)(wsrc + 8);
      __bf16* d = &Bs[0][0] + brow*264 + bseg*16;
      *(bf16x8*)d = a0; *(bf16x8*)(d + 8) = a1;
    }
    bf16x8 g0 = *(const bf16x8*)(wsrc + (size_t)4096);
    bf16x8 g1 = *(const bf16x8*)(wsrc + (size_t)4096 + 8);
    __syncthreads();

    #pragma unroll 1
    for (int s = 0; s < 8; ++s) {
      if (s < 7) {
        __bf16* d = &Bs[(s+1) & 1][0] + brow*264 + bseg*16;
        *(bf16x8*)d = g0; *(bf16x8*)(d + 8) = g1;
      }
      if (s < 6) {
        const __bf16* p = wsrc + (size_t)(s+2)*4096;
        g0 = *(const bf16x8*)p; g1 = *(const bf16x8*)(p + 8);
      }
      const __bf16* Ab = &Bs[s & 1][0] + col*264 + quad*8;
      f32x4 acc = zero;
      #pragma unroll
      for (int kk = 0; kk < 8; ++kk) {
        bf16x8 wf = *(const bf16x8*)(Ab + kk*32);
        acc = __builtin_amdgcn_mfma_f32_16x16x32_bf16(wf, bq[kk], acc, 0, 0, 0);
      }
      int nq4 = n0 + s*16 + quad*4;
      float4 b4 = *(const float4*)(qkvb + nq4);
      float bb[4] = {b4.x, b4.y, b4.z, b4.w};
      bf16x4 o;
      #pragma unroll
      for (int r = 0; r < 4; ++r) o[r] = (__bf16)((acc[r]+bb[r])*QSCALE_L2E);
      *(bf16x4*)(qbf + ((size_t)(m0 + col))*256 + nq4) = o;
      __syncthreads();
    }
  } else {
    // ---------------- mid/glb KV: direct f32 A-frags ----------------
    int v = u - 768;                   // 0..159: (tb 20, nq 4, b 2)
    int tb = v % 20, nq = (v / 20) & 3, b = v / 80;
    int m0 = tb*64 + wv*16;
    int n0 = nq*128;

    bf16x8 af[8];
    if (tb < 16) {
      const float* Abase = mid + ((size_t)(b*256))*1024 + (m0 + col);
      #pragma unroll
      for (int kk = 0; kk < 8; ++kk) {
        #pragma unroll
        for (int j = 0; j < 8; ++j)
          af[kk][j] = (__bf16)Abase[(size_t)(kk*32 + quad*8 + j)*1024];
      }
    } else {
      const float* Abase = glb + ((size_t)(b*256))*256 + (m0 - 1024 + col);
      #pragma unroll
      for (int kk = 0; kk < 8; ++kk) {
        #pragma unroll
        for (int j = 0; j < 8; ++j)
          af[kk][j] = (__bf16)Abase[(size_t)(kk*32 + quad*8 + j)*256];
      }
    }

    int brow = tid >> 4, bseg = tid & 15;
    const __bf16* wsrc = WT + ((size_t)(256 + n0 + brow))*256 + bseg*16;
    {
      bf16x8 a0 = *(const bf16x8*)wsrc;
      bf16x8 a1 = *(const bf16x8*)(wsrc + 8);
      __bf16* d = &Bs[0][0] + brow*264 + bseg*16;
      *(bf16x8*)d = a0; *(bf16x8*)(d + 8) = a1;
    }
    bf16x8 g0 = *(const bf16x8*)(wsrc + (size_t)4096);
    bf16x8 g1 = *(const bf16x8*)(wsrc + (size_t)4096 + 8);
    __syncthreads();

    #pragma unroll 1
    for (int s = 0; s < 8; ++s) {
      if (s < 7) {
        __bf16* d = &Bs[(s+1) & 1][0] + brow*264 + bseg*16;
        *(bf16x8*)d = g0; *(bf16x8*)(d + 8) = g1;
      }
      if (s < 6) {
        const __bf16* p = wsrc + (size_t)(s+2)*4096;
        g0 = *(const bf16x8*)p; g1 = *(const bf16x8*)(p + 8);
      }
      int n = n0 + s*16 + col;
      float bias_n = qkvb[256 + n];
      const __bf16* Bb = &Bs[s & 1][0] + col*264 + quad*8;
      f32x4 acc = zero;
      #pragma unroll
      for (int kk = 0; kk < 8; ++kk) {
        bf16x8 bv = *(const bf16x8*)(Bb + kk*32);
        acc = __builtin_amdgcn_mfma_f32_16x16x32_bf16(af[kk], bv, acc, 0, 0, 0);
      }
      if (n < 256) {
        #pragma unroll
        for (int r = 0; r < 4; ++r)
          kmg[((size_t)b*1280 + m0 + quad*4 + r)*256 + n] = (__bf16)(acc[r] + bias_n);
      } else {
        bf16x4 o;
        #pragma unroll
        for (int r = 0; r < 4; ++r) o[r] = (__bf16)(acc[r] + bias_n);
        *(bf16x4*)(vmgt + ((size_t)b*256 + (n - 256))*1280 + m0 + quad*4) = o;
      }
      __syncthreads();
    }
  }
}

// ---------------- MFMA fused attention: 128-token slabs (10 barriers) ----------------
__global__ __launch_bounds__(512) void attn_mfma(
    const __bf16* __restrict__ qbf, const __bf16* __restrict__ Kpad,
    const __bf16* __restrict__ VpadT, const __bf16* __restrict__ kmg,
    const __bf16* __restrict__ vmgt, __bf16* __restrict__ obf)
{
  __shared__ __bf16 Ks[2][128][40];     // 20.5 KB: 128 token rows x 32 dims (+pad)
  __shared__ __bf16 Vs[2][32][136];     // 17.4 KB: 32 dim rows x 128 tokens (+pad)
  int blk = blockIdx.x;
  int b = blk >> 8, rr = blk & 255;
  int h = rr >> 5, wg = rr & 31;
  int tid = threadIdx.x, wv = tid >> 6, lane = tid & 63;
  int col = lane & 15, quad = lane >> 4;
  int w = wg*8 + wv;                    // this wave's window (within batch)
  int bw = b*256 + w;

  // slab staging: each thread stages TWO 16B pieces per 128-token slab
  bool isK = tid < 256;
  int krow = tid >> 2,        kseg = tid & 3;          // 64 rows x 4 segs
  int vrow = (tid - 256) >> 3, vseg = (tid - 256) & 7; // 32 rows x 8 segs
  const __bf16* gbase;
  __bf16 *d0a, *d0b, *d1a, *d1b;
  size_t gslab, soff2;
  if (isK) {
    gbase = kmg + ((size_t)(b*1280 + krow))*256 + h*32 + kseg*8;
    gslab = (size_t)128*256;
    soff2 = (size_t)64*256;             // second piece: token krow+64
    d0a = &Ks[0][krow][kseg*8];    d0b = &Ks[0][64+krow][kseg*8];
    d1a = &Ks[1][krow][kseg*8];    d1b = &Ks[1][64+krow][kseg*8];
  } else {
    gbase = vmgt + ((size_t)(b*256 + h*32 + vrow))*1280 + vseg*8;
    gslab = 128;
    soff2 = 64;                         // second piece: tokens +64
    d0a = &Vs[0][vrow][vseg*8];    d0b = &Vs[0][vrow][64+vseg*8];
    d1a = &Vs[1][vrow][vseg*8];    d1b = &Vs[1][vrow][64+vseg*8];
  }

  bf16x8 aq = *(const bf16x8*)(qbf + ((size_t)(bw*16 + col))*256 + h*32 + quad*8);
  f32x4 O0 = {0.f,0.f,0.f,0.f}, O1 = {0.f,0.f,0.f,0.f};
  const f32x4 zero = {0.f,0.f,0.f,0.f};
  float ls = 0.f;                       // row-sum for q=col (this lane's 8 k-slots)

  // issue slab-0 loads early
  bf16x8 sa = *(const bf16x8*)gbase;
  bf16x8 sb = *(const bf16x8*)(gbase + soff2);

  // ---- local chunks 0,1: padded-pixel gathers ----
  int wy = w >> 4, wx = w & 15;
  int py = wy*4, px = wx*4;             // padded top-left of the 8x8 patch
  const __bf16* kb = Kpad + (size_t)b*KPAD_B + h*32 + quad*8;
  int kr = (py + (col >> 3))*68 + px + (col & 7);
  const __bf16* vp0 = VpadT + ((size_t)(b*256 + h*32 + col))*VROW;
  const __bf16* vp1 = vp0 + (size_t)16*VROW;
  int vr = (py + (quad >> 1))*68 + px + (quad & 1)*4;
  #pragma unroll
  for (int ch = 0; ch < 2; ++ch) {
    int ko = kr + ch*272;               // +ch*4 rows
    bf16x8 k0 = *(const bf16x8*)(kb + (size_t)ko*256);
    bf16x8 k1 = *(const bf16x8*)(kb + (size_t)(ko + 136)*256);   // +2 rows (=+16 tokens)
    int vo = vr + ch*272;
    bf16x4 va0 = *(const bf16x4*)(vp0 + vo);
    bf16x4 va1 = *(const bf16x4*)(vp0 + vo + 136);
    bf16x4 vb0 = *(const bf16x4*)(vp1 + vo);
    bf16x4 vb1 = *(const bf16x4*)(vp1 + vo + 136);
    f32x4 S0 = __builtin_amdgcn_mfma_f32_16x16x32_bf16(k0, aq, zero, 0, 0, 0);
    f32x4 S1 = __builtin_amdgcn_mfma_f32_16x16x32_bf16(k1, aq, zero, 0, 0, 0);
    bf16x8 pf;
    #pragma unroll
    for (int r = 0; r < 4; ++r) {
      float p0 = __builtin_amdgcn_exp2f(S0[r]);
      float p1 = __builtin_amdgcn_exp2f(S1[r]);
      ls += p0 + p1;
      pf[r] = (__bf16)p0; pf[4+r] = (__bf16)p1;
    }
    bf16x8 v0 = __builtin_shufflevector(va0, va1, 0,1,2,3,4,5,6,7);
    bf16x8 v1 = __builtin_shufflevector(vb0, vb1, 0,1,2,3,4,5,6,7);
    O0 = __builtin_amdgcn_mfma_f32_16x16x32_bf16(pf, v0, O0, 0, 0, 0);
    O1 = __builtin_amdgcn_mfma_f32_16x16x32_bf16(pf, v1, O1, 0, 0, 0);
  }

  // write slab 0 to buf0, prefetch slab 1
  *(bf16x8*)d0a = sa; *(bf16x8*)d0b = sb;
  sa = *(const bf16x8*)(gbase + gslab);
  sb = *(const bf16x8*)(gbase + gslab + soff2);
  __syncthreads();

  #pragma unroll 1
  for (int s = 0; s < 10; ++s) {
    if (s + 1 < 10) {
      if (s & 1) { *(bf16x8*)d0a = sa; *(bf16x8*)d0b = sb; }
      else       { *(bf16x8*)d1a = sa; *(bf16x8*)d1b = sb; }
      if (s + 2 < 10) {
        sa = *(const bf16x8*)(gbase + (size_t)(s+2)*gslab);
        sb = *(const bf16x8*)(gbase + (size_t)(s+2)*gslab + soff2);
      }
    }
    const __bf16* Kb = &Ks[s & 1][0][0];
    const __bf16* Vb = &Vs[s & 1][0][0];
    #pragma unroll
    for (int c = 0; c < 4; ++c) {
      bf16x8 k0 = *(const bf16x8*)(Kb + (c*32 + col)*40 + quad*8);
      bf16x8 k1 = *(const bf16x8*)(Kb + (c*32 + 16 + col)*40 + quad*8);
      bf16x4 va0 = *(const bf16x4*)(Vb + (size_t)col*136      + c*32 + quad*4);
      bf16x4 va1 = *(const bf16x4*)(Vb + (size_t)col*136      + c*32 + 16 + quad*4);
      bf16x4 vb0 = *(const bf16x4*)(Vb + (size_t)(16+col)*136 + c*32 + quad*4);
      bf16x4 vb1 = *(const bf16x4*)(Vb + (size_t)(16+col)*136 + c*32 + 16 + quad*4);
      f32x4 S0 = __builtin_amdgcn_mfma_f32_16x16x32_bf16(k0, aq, zero, 0, 0, 0);
      f32x4 S1 = __builtin_amdgcn_mfma_f32_16x16x32_bf16(k1, aq, zero, 0, 0, 0);
      bf16x8 pf;
      #pragma unroll
      for (int r = 0; r < 4; ++r) {
        float p0 = __builtin_amdgcn_exp2f(S0[r]);
        float p1 = __builtin_amdgcn_exp2f(S1[r]);
        ls += p0 + p1;
        pf[r] = (__bf16)p0; pf[4+r] = (__bf16)p1;
      }
      bf16x8 v0 = __builtin_shufflevector(va0, va1, 0,1,2,3,4,5,6,7);
      bf16x8 v1 = __builtin_shufflevector(vb0, vb1, 0,1,2,3,4,5,6,7);
      O0 = __builtin_amdgcn_mfma_f32_16x16x32_bf16(pf, v0, O0, 0, 0, 0);
      O1 = __builtin_amdgcn_mfma_f32_16x16x32_bf16(pf, v1, O1, 0, 0, 0);
    }
    __syncthreads();
  }

  // lanes (col, quad=0..3) partition the k-range of row q=col: reduce over quads
  ls += __shfl_xor(ls, 16);
  ls += __shfl_xor(ls, 32);
  // O0[r] is q=quad*4+r: fetch L[q] from lane (col'=q, quad'=0)
  __bf16* op = obf + ((size_t)(bw*16) + quad*4)*256 + h*32 + col;
  #pragma unroll
  for (int r = 0; r < 4; ++r) {
    float inv = 1.f / __shfl(ls, quad*4 + r);
    op[(size_t)r*256]      = (__bf16)(O0[r]*inv);
    op[(size_t)r*256 + 16] = (__bf16)(O1[r]*inv);
  }
}

// ---------------- out projection v4: 512 blocks (wave = one window) ----------------
// 2 blocks/CU (66 KB LDS each, 132 < 160 KB) doubles resident waves for both the
// MFMA phase and the F-residual streaming tail vs the 256-block version.
__global__ __launch_bounds__(256) void gemm_out_strip(
    const __bf16* __restrict__ obf, const __bf16* __restrict__ WoT,
    const float* __restrict__ outb, const float* __restrict__ Fres,
    float* __restrict__ Out)
{
  __shared__ __bf16 Bs4[4*16*264];     // 33 KB: this block's 4 WoT tiles
  __shared__ __bf16 strip[64*264];     // 33 KB (quarter used per block)
  int blk = blockIdx.x;                // b*256 + wy*16 + cq*4 + xh2
  int b = blk >> 8, rest = blk & 255;
  int wy = rest >> 4, cq = (rest >> 2) & 3, xh2 = rest & 3;
  int c0 = cq*64;
  int tid = threadIdx.x, wv = tid >> 6, lane = tid & 63;
  int col = lane & 15, quad = lane >> 4;
  const f32x4 zero = {0.f,0.f,0.f,0.f};

  {
    int brow = tid >> 4, bseg = tid & 15;
    const __bf16* wsrc = WoT + ((size_t)(c0 + brow))*256 + bseg*16;
    #pragma unroll
    for (int s = 0; s < 4; ++s) {
      bf16x8 a0 = *(const bf16x8*)(wsrc + (size_t)s*4096);
      bf16x8 a1 = *(const bf16x8*)(wsrc + (size_t)s*4096 + 8);
      __bf16* d = Bs4 + s*4224 + brow*264 + bseg*16;
      *(bf16x8*)d = a0; *(bf16x8*)(d + 8) = a1;
    }
  }
  __syncthreads();

  {
    int wx = xh2*4 + wv;               // this wave's window column
    int win = b*256 + wy*16 + wx;
    bf16x8 ao[8];
    const __bf16* op = obf + ((size_t)win*16 + col)*256 + quad*8;
    #pragma unroll
    for (int kk = 0; kk < 8; ++kk) ao[kk] = *(const bf16x8*)(op + kk*32);
    #pragma unroll
    for (int nt = 0; nt < 4; ++nt) {
      const __bf16* Bb = Bs4 + nt*4224 + col*264 + quad*8;
      f32x4 acc = zero;
      #pragma unroll
      for (int kk = 0; kk < 8; ++kk) {
        bf16x8 wf = *(const bf16x8*)(Bb + kk*32);
        acc = __builtin_amdgcn_mfma_f32_16x16x32_bf16(ao[kk], wf, acc, 0, 0, 0);
      }
      bf16x4 o;
      #pragma unroll
      for (int r = 0; r < 4; ++r) o[r] = (__bf16)acc[r];
      *(bf16x4*)&strip[(nt*16+col)*264 + quad*66 + wx*4] = o;
    }
  }
  __syncthreads();
  #pragma unroll
  for (int j = 0; j < 4; ++j) {
    int f4 = j*256 + tid;               // 1024 = 64c x 4y x 4xq
    int xq = (f4 & 3) + xh2*4, y = (f4 >> 2) & 3, c = f4 >> 4;
    bf16x4 d = *(const bf16x4*)&strip[c*264 + y*66 + xq*4];
    size_t off = ((size_t)(b*256 + c0 + c))*HWSZ + (wy*4 + y)*64 + xq*4;
    float4 r4 = *(const float4*)(Fres + off);
    float bn = outb[c0 + c];
    float4 o;
    o.x = (float)d[0] + bn + r4.x; o.y = (float)d[1] + bn + r4.y;
    o.z = (float)d[2] + bn + r4.z; o.w = (float)d[3] + bn + r4.w;
    *(float4*)(Out + off) = o;
  }
}

extern "C" void kernel_launch(void* const* d_in, const int* in_sizes, int n_in,
                              void* d_out, int out_size, void* d_ws, size_t ws_size,
                              hipStream_t stream) {
  const float* F     = (const float*)d_in[0];
  const float* qkv_w = (const float*)d_in[1];
  const float* qkv_b = (const float*)d_in[2];
  const float* out_w = (const float*)d_in[3];
  const float* out_b = (const float*)d_in[4];
  const float* ln_w  = (const float*)d_in[5];
  const float* ln_b  = (const float*)d_in[6];
  float* out = (float*)d_out;

  __bf16* qnb   = (__bf16*)d_ws;             // 2,097,152 h
  __bf16* qbf   = qnb   + 2097152;           // 2,097,152 h
  __bf16* obf   = qbf   + 2097152;           // 2,097,152 h
  __bf16* Kpad  = obf   + 2097152;           // 2,367,488 h (2*68*68*256)
  __bf16* VpadT = Kpad  + 2367488;           // 2,367,488 h
  __bf16* kmg   = VpadT + 2367488;           // 655,360 h
  __bf16* vmgt  = kmg   + 655360;            // 655,360 h
  __bf16* WT    = vmgt  + 655360;            // 196,608 h
  __bf16* WoT   = WT    + 196608;            // 65,536 h
  float*  mid   = (float*)(WoT + 65536);     // 524,288 f
  float*  glb   = mid   + 524288;            // 131,072 f

  fused_pre<<<624, 256, 0, stream>>>(F, ln_w, ln_b, qnb, mid, glb,
                                     qkv_w, out_w, WT, WoT, qkv_b,
                                     Kpad, VpadT);
  fused_gemms<<<928, 256, 0, stream>>>(F, qnb, mid, glb, WT, qkv_b,
                                       qbf, Kpad, VpadT, kmg, vmgt);
  attn_mfma<<<512, 512, 0, stream>>>(qbf, Kpad, VpadT, kmg, vmgt, obf);
  gemm_out_strip<<<512, 256, 0, stream>>>(obf, WoT, out_b, F, out);
}

// Round 9
// 123.240 us; speedup vs baseline: 1.1865x; 1.0015x over previous
//
#include <hip/hip_runtime.h>
#include <math.h>

#define HWSZ 4096   // 64*64
// 1/sqrt(32) * log2(e): scores come out pre-multiplied by log2(e), so softmax
// uses p = exp2(S) (single v_exp_f32) -- mathematically identical.
#define QSCALE_L2E 0.25501988932587245f

typedef __bf16 bf16x2 __attribute__((ext_vector_type(2)));
typedef __bf16 bf16x4 __attribute__((ext_vector_type(4)));
typedef __bf16 bf16x8 __attribute__((ext_vector_type(8)));
typedef float  f32x4  __attribute__((ext_vector_type(4)));

// K_pad: [b][68][68][256] token-major padded K (halo = K-bias vector)
// V_padT: [b][256][68][68] dim-major padded V (halo = V-bias value)
#define KPAD_B 1183744   // 68*68*256
#define VROW   4624      // 68*68

// Barrier that orders LDS only: __syncthreads() forces the compiler to emit
// s_waitcnt vmcnt(0) before s_barrier, draining in-flight global prefetches
// and scattered stores every loop iteration (the m97-style stall). The
// double-buffer hazards here are LDS-only, so lgkmcnt(0) + raw s_barrier
// suffices; global loads/stores stay in flight across the barrier.
__device__ __forceinline__ void fast_barrier() {
  asm volatile("s_waitcnt lgkmcnt(0)" ::: "memory");
  __builtin_amdgcn_s_barrier();
  __builtin_amdgcn_sched_barrier(0);
}

// ================= stage 1 fused =================
// blocks 0-511:   LayerNorm strip + fused pools
// blocks 512-575: weight transposes (qkv_w -> WT, out_w -> WoT)
// blocks 576-607: K_pad bias fill  (interior overwritten by kv_pix GEMM)
// blocks 608-623: V_padT bias fill
__global__ __launch_bounds__(256) void fused_pre(
    const float* __restrict__ F, const float* __restrict__ lnw,
    const float* __restrict__ lnb, __bf16* __restrict__ qnb,
    float* __restrict__ mid, float* __restrict__ glb,
    const float* __restrict__ Wqkv, const float* __restrict__ Wout,
    __bf16* __restrict__ WT, __bf16* __restrict__ WoT,
    const float* __restrict__ qkvb,
    __bf16* __restrict__ Kpad, __bf16* __restrict__ VpadT)
{
  __shared__ float sbuf[64*68];        // union: ln needs 16*269=4304f, wtrans 64*68=4352f
  int u = blockIdx.x;
  int tid = threadIdx.x;
  if (u < 512) {
    // ---------------- LayerNorm + pools ----------------
    float* sm = sbuf;                  // [c16] stride 269, [py] stride 67, [x]
    int blk = u;                       // b*256 + wy*16 + t
    int b = blk >> 8, wy = (blk >> 4) & 15, t = blk & 15;
    const float* Fb = F + ((size_t)(b*256 + t*16))*HWSZ + (wy*4)*64;
    int py = tid >> 6, x = tid & 63;
    #pragma unroll
    for (int j = 0; j < 16; ++j)
      sm[j*269 + py*67 + x] = Fb[(size_t)j*HWSZ + py*64 + x];
    __syncthreads();

    // pools from the staged RAW strip: this block owns mid rows wy*2,wy*2+1
    // and glb row wy for channels t*16..t*16+15.
    {
      int j = tid >> 4, u16 = tid & 15;
      const float* r0 = &sm[j*269];            // py stride 67
      int xb = u16*4;
      float m00 = 0.25f*(r0[xb]      + r0[xb+1]    + r0[67+xb]   + r0[67+xb+1]);
      float m01 = 0.25f*(r0[xb+2]    + r0[xb+3]    + r0[67+xb+2] + r0[67+xb+3]);
      float m10 = 0.25f*(r0[134+xb]  + r0[134+xb+1]+ r0[201+xb]  + r0[201+xb+1]);
      float m11 = 0.25f*(r0[134+xb+2]+ r0[134+xb+3]+ r0[201+xb+2]+ r0[201+xb+3]);
      int c = t*16 + j;
      float* mp = mid + ((size_t)(b*256 + c))*1024 + (wy*2)*32 + u16*2;
      *(float2*)mp        = make_float2(m00, m01);
      *(float2*)(mp + 32) = make_float2(m10, m11);
      glb[((size_t)(b*256 + c))*256 + wy*16 + u16] = 0.25f*(m00 + m01 + m10 + m11);
    }

    int wx = tid >> 4, cl = tid & 15;  // window wx, channel-lane cl
    float vals[16], s1 = 0.f, s2 = 0.f;
    #pragma unroll
    for (int p = 0; p < 16; ++p) {
      float v = sm[cl*269 + (p >> 2)*67 + wx*4 + (p & 3)];
      vals[p] = v; s1 += v; s2 += v*v;
    }
    #pragma unroll
    for (int m = 1; m < 16; m <<= 1) { s1 += __shfl_xor(s1, m); s2 += __shfl_xor(s2, m); }
    float mean = s1 * (1.f/256.f);
    float var  = s2 * (1.f/256.f) - mean*mean;
    float rstd = rsqrtf(var + 1e-5f);
    __bf16* outp = qnb + (((size_t)(b*256 + wy*16 + wx))*16 + t)*256 + cl*16;
    bf16x8 o0, o1;
    #pragma unroll
    for (int p = 0; p < 8; ++p) {
      o0[p] = (__bf16)((vals[p]  -mean)*rstd*lnw[cl*16+p]   + lnb[cl*16+p]);
      o1[p] = (__bf16)((vals[p+8]-mean)*rstd*lnw[cl*16+p+8] + lnb[cl*16+p+8]);
    }
    *(bf16x8*)outp = o0;
    *(bf16x8*)(outp+8) = o1;
  } else if (u < 576) {
    // ---------------- weight transposes ----------------
    float (*T)[68] = (float(*)[68])sbuf;
    int v = u - 512;                   // 0..63: bx = v&15, k-block = v>>4
    int bx = v & 15, k0 = (v >> 4)*64;
    int c4 = (tid & 15)*4, rr = tid >> 4;
    const float* W; __bf16* D; int ncols, n0;
    if (bx < 12) { W = Wqkv; D = WT;  ncols = 768; n0 = bx*64; }
    else         { W = Wout; D = WoT; ncols = 256; n0 = (bx-12)*64; }
    #pragma unroll
    for (int p = 0; p < 4; ++p) {
      int row = p*16 + rr;
      float4 vv = *(const float4*)(W + (size_t)(k0+row)*ncols + n0 + c4);
      T[c4+0][row] = vv.x; T[c4+1][row] = vv.y; T[c4+2][row] = vv.z; T[c4+3][row] = vv.w;
    }
    __syncthreads();
    #pragma unroll
    for (int p = 0; p < 4; ++p) {
      int cc = p*16 + rr;
      bf16x4 o;
      o[0] = (__bf16)T[cc][c4+0]; o[1] = (__bf16)T[cc][c4+1];
      o[2] = (__bf16)T[cc][c4+2]; o[3] = (__bf16)T[cc][c4+3];
      *(bf16x4*)(D + (size_t)(n0+cc)*256 + k0 + c4) = o;
    }
  } else if (u < 608) {
    // ---------------- K_pad bias fill ----------------
    int gid = (u - 576)*256 + tid;     // 0..8191
    int nv = gid & 31;                 // fixed vec8 slot within 256 dims
    bf16x8 kv;
    #pragma unroll
    for (int j = 0; j < 8; ++j) kv[j] = (__bf16)qkvb[256 + nv*8 + j];
    for (int pos = gid >> 5; pos < 9248; pos += 256)
      *(bf16x8*)(Kpad + (size_t)pos*256 + nv*8) = kv;
  } else {
    // ---------------- V_padT bias fill ----------------
    int gid = (u - 608)*256 + tid;     // 0..4095
    int row = gid >> 3, sub = gid & 7; // row = b*256 + dim, 8 threads/row
    __bf16 vvs = (__bf16)qkvb[512 + (row & 255)];
    bf16x8 vv;
    #pragma unroll
    for (int j = 0; j < 8; ++j) vv[j] = vvs;
    __bf16* dst = VpadT + (size_t)row*VROW;
    for (int s = sub; s < 578; s += 8)
      *(bf16x8*)(dst + s*8) = vv;
  }
}

// ================= stage 2 fused: the three projection GEMMs =================
// (R4 structure; loop barriers are LDS-only fast_barrier so the g0/g1
// prefetches and the scattered K/V stores stay in flight across iterations)
// blocks 0-511:   kv_pix: per-pixel K/V projection into padded arrays.
// blocks 512-767: q GEMM (WT[0:256] LDS-staged)
// blocks 768-927: mid/glb KV (direct f32 A-frag loads)
__global__ __launch_bounds__(256) void fused_gemms(
    const float* __restrict__ F, const __bf16* __restrict__ qnb,
    const float* __restrict__ mid, const float* __restrict__ glb,
    const __bf16* __restrict__ WT, const float* __restrict__ qkvb,
    __bf16* __restrict__ qbf, __bf16* __restrict__ Kpad,
    __bf16* __restrict__ VpadT, __bf16* __restrict__ kmg,
    __bf16* __restrict__ vmgt)
{
  __shared__ __bf16 Bs[2][16*264];     // 16.5 KB, shared by all branches
  int u = blockIdx.x;
  int tid = threadIdx.x;
  int wv = tid >> 6, lane = tid & 63;
  int col = lane & 15, quad = lane >> 4;
  const f32x4 zero = {0.f,0.f,0.f,0.f};

  if (u < 512) {
    // ---------------- kv_pix ----------------
    int mb = u >> 2, ns = u & 3;       // mb: b*64 + y ; ns: N-split
    int b = mb >> 6, y = mb & 63;
    int x0w = wv*16;                   // wave's x-offset within the row

    // A-frags: af[kk][j] = F[b][kk*32+quad*8+j][y][x0w+col]  (coalesced over col)
    bf16x8 af[8];
    const float* Fb = F + ((size_t)(b*256))*HWSZ + y*64 + x0w + col;
    #pragma unroll
    for (int kk = 0; kk < 8; ++kk) {
      #pragma unroll
      for (int j = 0; j < 8; ++j)
        af[kk][j] = (__bf16)Fb[(size_t)(kk*32 + quad*8 + j)*HWSZ];
    }

    int brow = tid >> 4, bseg = tid & 15;
    const __bf16* wsrc = WT + ((size_t)(256 + ns*128 + brow))*256 + bseg*16;
    {
      bf16x8 a0 = *(const bf16x8*)wsrc;
      bf16x8 a1 = *(const bf16x8*)(wsrc + 8);
      __bf16* d = &Bs[0][0] + brow*264 + bseg*16;
      *(bf16x8*)d = a0; *(bf16x8*)(d + 8) = a1;
    }
    bf16x8 g0 = *(const bf16x8*)(wsrc + (size_t)4096);
    bf16x8 g1 = *(const bf16x8*)(wsrc + (size_t)4096 + 8);
    fast_barrier();

    bool isK = (ns < 2);
    #pragma unroll 1
    for (int nt = 0; nt < 8; ++nt) {
      if (nt < 7) {
        __bf16* d = &Bs[(nt+1) & 1][0] + brow*264 + bseg*16;
        *(bf16x8*)d = g0; *(bf16x8*)(d + 8) = g1;
      }
      if (nt < 6) {
        const __bf16* p = wsrc + (size_t)(nt+2)*4096;
        g0 = *(const bf16x8*)p; g1 = *(const bf16x8*)(p + 8);
      }
      const __bf16* Bb = &Bs[nt & 1][0] + col*264 + quad*8;
      f32x4 acc = zero;
      if (isK) {
        #pragma unroll
        for (int kk = 0; kk < 8; ++kk) {
          bf16x8 bv = *(const bf16x8*)(Bb + kk*32);
          acc = __builtin_amdgcn_mfma_f32_16x16x32_bf16(af[kk], bv, acc, 0, 0, 0);
        }
        int n = ns*128 + nt*16 + col;
        float bias_n = qkvb[256 + n];
        #pragma unroll
        for (int r = 0; r < 4; ++r) {
          int x = x0w + quad*4 + r;
          Kpad[(size_t)b*KPAD_B + ((size_t)(y+2)*68 + (x+2))*256 + n]
              = (__bf16)(acc[r] + bias_n);
        }
      } else {
        #pragma unroll
        for (int kk = 0; kk < 8; ++kk) {
          bf16x8 bv = *(const bf16x8*)(Bb + kk*32);
          acc = __builtin_amdgcn_mfma_f32_16x16x32_bf16(bv, af[kk], acc, 0, 0, 0);
        }
        int x = x0w + col;
        #pragma unroll
        for (int r = 0; r < 4; ++r) {
          int dim = (ns - 2)*128 + nt*16 + quad*4 + r;
          float bias_d = qkvb[512 + dim];
          VpadT[((size_t)(b*256 + dim))*VROW + (size_t)(y+2)*68 + (x+2)]
              = (__bf16)(acc[r] + bias_d);
        }
      }
      fast_barrier();
    }
  } else if (u < 768) {
    // ---------------- q GEMM ----------------
    int blk = u - 512;                 // tb*2 + nh
    int tb = blk >> 1, nh = blk & 1;
    int n0 = nh*128;
    int m0 = tb*64 + wv*16;

    bf16x8 bq[8];
    const __bf16* qp = qnb + ((size_t)(m0 + col))*256 + quad*8;
    #pragma unroll
    for (int kk = 0; kk < 8; ++kk) bq[kk] = *(const bf16x8*)(qp + kk*32);

    int brow = tid >> 4, bseg = tid & 15;
    const __bf16* wsrc = WT + ((size_t)(n0 + brow))*256 + bseg*16;
    {
      bf16x8 a0 = *(const bf16x8*)wsrc;
      bf16x8 a1 = *(const bf16x8*)(wsrc + 8);
      __bf16* d = &Bs[0][0] + brow*264 + bseg*16;
      *(bf16x8*)d = a0; *(bf16x8*)(d + 8) = a1;
    }
    bf16x8 g0 = *(const bf16x8*)(wsrc + (size_t)4096);
    bf16x8 g1 = *(const bf16x8*)(wsrc + (size_t)4096 + 8);
    fast_barrier();

    #pragma unroll 1
    for (int s = 0; s < 8; ++s) {
      if (s < 7) {
        __bf16* d = &Bs[(s+1) & 1][0] + brow*264 + bseg*16;
        *(bf16x8*)d = g0; *(bf16x8*)(d + 8) = g1;
      }
      if (s < 6) {
        const __bf16* p = wsrc + (size_t)(s+2)*4096;
        g0 = *(const bf16x8*)p; g1 = *(const bf16x8*)(p + 8);
      }
      const __bf16* Ab = &Bs[s & 1][0] + col*264 + quad*8;
      f32x4 acc = zero;
      #pragma unroll
      for (int kk = 0; kk < 8; ++kk) {
        bf16x8 wf = *(const bf16x8*)(Ab + kk*32);
        acc = __builtin_amdgcn_mfma_f32_16x16x32_bf16(wf, bq[kk], acc, 0, 0, 0);
      }
      int nq4 = n0 + s*16 + quad*4;
      float4 b4 = *(const float4*)(qkvb + nq4);
      float bb[4] = {b4.x, b4.y, b4.z, b4.w};
      bf16x4 o;
      #pragma unroll
      for (int r = 0; r < 4; ++r) o[r] = (__bf16)((acc[r]+bb[r])*QSCALE_L2E);
      *(bf16x4*)(qbf + ((size_t)(m0 + col))*256 + nq4) = o;
      fast_barrier();
    }
  } else {
    // ---------------- mid/glb KV: direct f32 A-frags ----------------
    int v = u - 768;                   // 0..159: (tb 20, nq 4, b 2)
    int tb = v % 20, nq = (v / 20) & 3, b = v / 80;
    int m0 = tb*64 + wv*16;
    int n0 = nq*128;

    bf16x8 af[8];
    if (tb < 16) {
      const float* Abase = mid + ((size_t)(b*256))*1024 + (m0 + col);
      #pragma unroll
      for (int kk = 0; kk < 8; ++kk) {
        #pragma unroll
        for (int j = 0; j < 8; ++j)
          af[kk][j] = (__bf16)Abase[(size_t)(kk*32 + quad*8 + j)*1024];
      }
    } else {
      const float* Abase = glb + ((size_t)(b*256))*256 + (m0 - 1024 + col);
      #pragma unroll
      for (int kk = 0; kk < 8; ++kk) {
        #pragma unroll
        for (int j = 0; j < 8; ++j)
          af[kk][j] = (__bf16)Abase[(size_t)(kk*32 + quad*8 + j)*256];
      }
    }

    int brow = tid >> 4, bseg = tid & 15;
    const __bf16* wsrc = WT + ((size_t)(256 + n0 + brow))*256 + bseg*16;
    {
      bf16x8 a0 = *(const bf16x8*)wsrc;
      bf16x8 a1 = *(const bf16x8*)(wsrc + 8);
      __bf16* d = &Bs[0][0] + brow*264 + bseg*16;
      *(bf16x8*)d = a0; *(bf16x8*)(d + 8) = a1;
    }
    bf16x8 g0 = *(const bf16x8*)(wsrc + (size_t)4096);
    bf16x8 g1 = *(const bf16x8*)(wsrc + (size_t)4096 + 8);
    fast_barrier();

    #pragma unroll 1
    for (int s = 0; s < 8; ++s) {
      if (s < 7) {
        __bf16* d = &Bs[(s+1) & 1][0] + brow*264 + bseg*16;
        *(bf16x8*)d = g0; *(bf16x8*)(d + 8) = g1;
      }
      if (s < 6) {
        const __bf16* p = wsrc + (size_t)(s+2)*4096;
        g0 = *(const bf16x8*)p; g1 = *(const bf16x8*)(p + 8);
      }
      int n = n0 + s*16 + col;
      float bias_n = qkvb[256 + n];
      const __bf16* Bb = &Bs[s & 1][0] + col*264 + quad*8;
      f32x4 acc = zero;
      #pragma unroll
      for (int kk = 0; kk < 8; ++kk) {
        bf16x8 bv = *(const bf16x8*)(Bb + kk*32);
        acc = __builtin_amdgcn_mfma_f32_16x16x32_bf16(af[kk], bv, acc, 0, 0, 0);
      }
      if (n < 256) {
        #pragma unroll
        for (int r = 0; r < 4; ++r)
          kmg[((size_t)b*1280 + m0 + quad*4 + r)*256 + n] = (__bf16)(acc[r] + bias_n);
      } else {
        bf16x4 o;
        #pragma unroll
        for (int r = 0; r < 4; ++r) o[r] = (__bf16)(acc[r] + bias_n);
        *(bf16x4*)(vmgt + ((size_t)b*256 + (n - 256))*1280 + m0 + quad*4) = o;
      }
      fast_barrier();
    }
  }
}

// ---------------- MFMA fused attention: 128-token slabs, LDS-only barriers ----------------
// The slab-(s+2) prefetch loads (sa/sb) now stay in flight across the barrier
// instead of being drained by __syncthreads' implicit vmcnt(0).
__global__ __launch_bounds__(512) void attn_mfma(
    const __bf16* __restrict__ qbf, const __bf16* __restrict__ Kpad,
    const __bf16* __restrict__ VpadT, const __bf16* __restrict__ kmg,
    const __bf16* __restrict__ vmgt, __bf16* __restrict__ obf)
{
  __shared__ __bf16 Ks[2][128][40];     // 20.5 KB: 128 token rows x 32 dims (+pad)
  __shared__ __bf16 Vs[2][32][136];     // 17.4 KB: 32 dim rows x 128 tokens (+pad)
  int blk = blockIdx.x;
  int b = blk >> 8, rr = blk & 255;
  int h = rr >> 5, wg = rr & 31;
  int tid = threadIdx.x, wv = tid >> 6, lane = tid & 63;
  int col = lane & 15, quad = lane >> 4;
  int w = wg*8 + wv;                    // this wave's window (within batch)
  int bw = b*256 + w;

  // slab staging: each thread stages TWO 16B pieces per 128-token slab
  bool isK = tid < 256;
  int krow = tid >> 2,        kseg = tid & 3;          // 64 rows x 4 segs
  int vrow = (tid - 256) >> 3, vseg = (tid - 256) & 7; // 32 rows x 8 segs
  const __bf16* gbase;
  __bf16 *d0a, *d0b, *d1a, *d1b;
  size_t gslab, soff2;
  if (isK) {
    gbase = kmg + ((size_t)(b*1280 + krow))*256 + h*32 + kseg*8;
    gslab = (size_t)128*256;
    soff2 = (size_t)64*256;             // second piece: token krow+64
    d0a = &Ks[0][krow][kseg*8];    d0b = &Ks[0][64+krow][kseg*8];
    d1a = &Ks[1][krow][kseg*8];    d1b = &Ks[1][64+krow][kseg*8];
  } else {
    gbase = vmgt + ((size_t)(b*256 + h*32 + vrow))*1280 + vseg*8;
    gslab = 128;
    soff2 = 64;                         // second piece: tokens +64
    d0a = &Vs[0][vrow][vseg*8];    d0b = &Vs[0][vrow][64+vseg*8];
    d1a = &Vs[1][vrow][vseg*8];    d1b = &Vs[1][vrow][64+vseg*8];
  }

  bf16x8 aq = *(const bf16x8*)(qbf + ((size_t)(bw*16 + col))*256 + h*32 + quad*8);
  f32x4 O0 = {0.f,0.f,0.f,0.f}, O1 = {0.f,0.f,0.f,0.f};
  const f32x4 zero = {0.f,0.f,0.f,0.f};
  float ls = 0.f;                       // row-sum for q=col (this lane's 8 k-slots)

  // issue slab-0 loads early
  bf16x8 sa = *(const bf16x8*)gbase;
  bf16x8 sb = *(const bf16x8*)(gbase + soff2);

  // ---- local chunks 0,1: padded-pixel gathers ----
  int wy = w >> 4, wx = w & 15;
  int py = wy*4, px = wx*4;             // padded top-left of the 8x8 patch
  const __bf16* kb = Kpad + (size_t)b*KPAD_B + h*32 + quad*8;
  int kr = (py + (col >> 3))*68 + px + (col & 7);
  const __bf16* vp0 = VpadT + ((size_t)(b*256 + h*32 + col))*VROW;
  const __bf16* vp1 = vp0 + (size_t)16*VROW;
  int vr = (py + (quad >> 1))*68 + px + (quad & 1)*4;
  #pragma unroll
  for (int ch = 0; ch < 2; ++ch) {
    int ko = kr + ch*272;               // +ch*4 rows
    bf16x8 k0 = *(const bf16x8*)(kb + (size_t)ko*256);
    bf16x8 k1 = *(const bf16x8*)(kb + (size_t)(ko + 136)*256);   // +2 rows (=+16 tokens)
    int vo = vr + ch*272;
    bf16x4 va0 = *(const bf16x4*)(vp0 + vo);
    bf16x4 va1 = *(const bf16x4*)(vp0 + vo + 136);
    bf16x4 vb0 = *(const bf16x4*)(vp1 + vo);
    bf16x4 vb1 = *(const bf16x4*)(vp1 + vo + 136);
    f32x4 S0 = __builtin_amdgcn_mfma_f32_16x16x32_bf16(k0, aq, zero, 0, 0, 0);
    f32x4 S1 = __builtin_amdgcn_mfma_f32_16x16x32_bf16(k1, aq, zero, 0, 0, 0);
    bf16x8 pf;
    #pragma unroll
    for (int r = 0; r < 4; ++r) {
      float p0 = __builtin_amdgcn_exp2f(S0[r]);
      float p1 = __builtin_amdgcn_exp2f(S1[r]);
      ls += p0 + p1;
      pf[r] = (__bf16)p0; pf[4+r] = (__bf16)p1;
    }
    bf16x8 v0 = __builtin_shufflevector(va0, va1, 0,1,2,3,4,5,6,7);
    bf16x8 v1 = __builtin_shufflevector(vb0, vb1, 0,1,2,3,4,5,6,7);
    O0 = __builtin_amdgcn_mfma_f32_16x16x32_bf16(pf, v0, O0, 0, 0, 0);
    O1 = __builtin_amdgcn_mfma_f32_16x16x32_bf16(pf, v1, O1, 0, 0, 0);
  }

  // write slab 0 to buf0, prefetch slab 1
  *(bf16x8*)d0a = sa; *(bf16x8*)d0b = sb;
  sa = *(const bf16x8*)(gbase + gslab);
  sb = *(const bf16x8*)(gbase + gslab + soff2);
  fast_barrier();

  #pragma unroll 1
  for (int s = 0; s < 10; ++s) {
    if (s + 1 < 10) {
      if (s & 1) { *(bf16x8*)d0a = sa; *(bf16x8*)d0b = sb; }
      else       { *(bf16x8*)d1a = sa; *(bf16x8*)d1b = sb; }
      if (s + 2 < 10) {
        sa = *(const bf16x8*)(gbase + (size_t)(s+2)*gslab);
        sb = *(const bf16x8*)(gbase + (size_t)(s+2)*gslab + soff2);
      }
    }
    const __bf16* Kb = &Ks[s & 1][0][0];
    const __bf16* Vb = &Vs[s & 1][0][0];
    #pragma unroll
    for (int c = 0; c < 4; ++c) {
      bf16x8 k0 = *(const bf16x8*)(Kb + (c*32 + col)*40 + quad*8);
      bf16x8 k1 = *(const bf16x8*)(Kb + (c*32 + 16 + col)*40 + quad*8);
      bf16x4 va0 = *(const bf16x4*)(Vb + (size_t)col*136      + c*32 + quad*4);
      bf16x4 va1 = *(const bf16x4*)(Vb + (size_t)col*136      + c*32 + 16 + quad*4);
      bf16x4 vb0 = *(const bf16x4*)(Vb + (size_t)(16+col)*136 + c*32 + quad*4);
      bf16x4 vb1 = *(const bf16x4*)(Vb + (size_t)(16+col)*136 + c*32 + 16 + quad*4);
      f32x4 S0 = __builtin_amdgcn_mfma_f32_16x16x32_bf16(k0, aq, zero, 0, 0, 0);
      f32x4 S1 = __builtin_amdgcn_mfma_f32_16x16x32_bf16(k1, aq, zero, 0, 0, 0);
      bf16x8 pf;
      #pragma unroll
      for (int r = 0; r < 4; ++r) {
        float p0 = __builtin_amdgcn_exp2f(S0[r]);
        float p1 = __builtin_amdgcn_exp2f(S1[r]);
        ls += p0 + p1;
        pf[r] = (__bf16)p0; pf[4+r] = (__bf16)p1;
      }
      bf16x8 v0 = __builtin_shufflevector(va0, va1, 0,1,2,3,4,5,6,7);
      bf16x8 v1 = __builtin_shufflevector(vb0, vb1, 0,1,2,3,4,5,6,7);
      O0 = __builtin_amdgcn_mfma_f32_16x16x32_bf16(pf, v0, O0, 0, 0, 0);
      O1 = __builtin_amdgcn_mfma_f32_16x16x32_bf16(pf, v1, O1, 0, 0, 0);
    }
    fast_barrier();
  }

  // lanes (col, quad=0..3) partition the k-range of row q=col: reduce over quads
  ls += __shfl_xor(ls, 16);
  ls += __shfl_xor(ls, 32);
  // O0[r] is q=quad*4+r: fetch L[q] from lane (col'=q, quad'=0)
  __bf16* op = obf + ((size_t)(bw*16) + quad*4)*256 + h*32 + col;
  #pragma unroll
  for (int r = 0; r < 4; ++r) {
    float inv = 1.f / __shfl(ls, quad*4 + r);
    op[(size_t)r*256]      = (__bf16)(O0[r]*inv);
    op[(size_t)r*256 + 16] = (__bf16)(O1[r]*inv);
  }
}

// ---------------- out projection v4: 512 blocks (wave = one window) ----------------
__global__ __launch_bounds__(256) void gemm_out_strip(
    const __bf16* __restrict__ obf, const __bf16* __restrict__ WoT,
    const float* __restrict__ outb, const float* __restrict__ Fres,
    float* __restrict__ Out)
{
  __shared__ __bf16 Bs4[4*16*264];     // 33 KB: this block's 4 WoT tiles
  __shared__ __bf16 strip[64*264];     // 33 KB (quarter used per block)
  int blk = blockIdx.x;                // b*256 + wy*16 + cq*4 + xh2
  int b = blk >> 8, rest = blk & 255;
  int wy = rest >> 4, cq = (rest >> 2) & 3, xh2 = rest & 3;
  int c0 = cq*64;
  int tid = threadIdx.x, wv = tid >> 6, lane = tid & 63;
  int col = lane & 15, quad = lane >> 4;
  const f32x4 zero = {0.f,0.f,0.f,0.f};

  {
    int brow = tid >> 4, bseg = tid & 15;
    const __bf16* wsrc = WoT + ((size_t)(c0 + brow))*256 + bseg*16;
    #pragma unroll
    for (int s = 0; s < 4; ++s) {
      bf16x8 a0 = *(const bf16x8*)(wsrc + (size_t)s*4096);
      bf16x8 a1 = *(const bf16x8*)(wsrc + (size_t)s*4096 + 8);
      __bf16* d = Bs4 + s*4224 + brow*264 + bseg*16;
      *(bf16x8*)d = a0; *(bf16x8*)(d + 8) = a1;
    }
  }
  __syncthreads();

  {
    int wx = xh2*4 + wv;               // this wave's window column
    int win = b*256 + wy*16 + wx;
    bf16x8 ao[8];
    const __bf16* op = obf + ((size_t)win*16 + col)*256 + quad*8;
    #pragma unroll
    for (int kk = 0; kk < 8; ++kk) ao[kk] = *(const bf16x8*)(op + kk*32);
    #pragma unroll
    for (int nt = 0; nt < 4; ++nt) {
      const __bf16* Bb = Bs4 + nt*4224 + col*264 + quad*8;
      f32x4 acc = zero;
      #pragma unroll
      for (int kk = 0; kk < 8; ++kk) {
        bf16x8 wf = *(const bf16x8*)(Bb + kk*32);
        acc = __builtin_amdgcn_mfma_f32_16x16x32_bf16(ao[kk], wf, acc, 0, 0, 0);
      }
      bf16x4 o;
      #pragma unroll
      for (int r = 0; r < 4; ++r) o[r] = (__bf16)acc[r];
      *(bf16x4*)&strip[(nt*16+col)*264 + quad*66 + wx*4] = o;
    }
  }
  __syncthreads();
  #pragma unroll
  for (int j = 0; j < 4; ++j) {
    int f4 = j*256 + tid;               // 1024 = 64c x 4y x 4xq
    int xq = (f4 & 3) + xh2*4, y = (f4 >> 2) & 3, c = f4 >> 4;
    bf16x4 d = *(const bf16x4*)&strip[c*264 + y*66 + xq*4];
    size_t off = ((size_t)(b*256 + c0 + c))*HWSZ + (wy*4 + y)*64 + xq*4;
    float4 r4 = *(const float4*)(Fres + off);
    float bn = outb[c0 + c];
    float4 o;
    o.x = (float)d[0] + bn + r4.x; o.y = (float)d[1] + bn + r4.y;
    o.z = (float)d[2] + bn + r4.z; o.w = (float)d[3] + bn + r4.w;
    *(float4*)(Out + off) = o;
  }
}

extern "C" void kernel_launch(void* const* d_in, const int* in_sizes, int n_in,
                              void* d_out, int out_size, void* d_ws, size_t ws_size,
                              hipStream_t stream) {
  const float* F     = (const float*)d_in[0];
  const float* qkv_w = (const float*)d_in[1];
  const float* qkv_b = (const float*)d_in[2];
  const float* out_w = (const float*)d_in[3];
  const float* out_b = (const float*)d_in[4];
  const float* ln_w  = (const float*)d_in[5];
  const float* ln_b  = (const float*)d_in[6];
  float* out = (float*)d_out;

  __bf16* qnb   = (__bf16*)d_ws;             // 2,097,152 h
  __bf16* qbf   = qnb   + 2097152;           // 2,097,152 h
  __bf16* obf   = qbf   + 2097152;           // 2,097,152 h
  __bf16* Kpad  = obf   + 2097152;           // 2,367,488 h (2*68*68*256)
  __bf16* VpadT = Kpad  + 2367488;           // 2,367,488 h
  __bf16* kmg   = VpadT + 2367488;           // 655,360 h
  __bf16* vmgt  = kmg   + 655360;            // 655,360 h
  __bf16* WT    = vmgt  + 655360;            // 196,608 h
  __bf16* WoT   = WT    + 196608;            // 65,536 h
  float*  mid   = (float*)(WoT + 65536);     // 524,288 f
  float*  glb   = mid   + 524288;            // 131,072 f

  fused_pre<<<624, 256, 0, stream>>>(F, ln_w, ln_b, qnb, mid, glb,
                                     qkv_w, out_w, WT, WoT, qkv_b,
                                     Kpad, VpadT);
  fused_gemms<<<928, 256, 0, stream>>>(F, qnb, mid, glb, WT, qkv_b,
                                       qbf, Kpad, VpadT, kmg, vmgt);
  attn_mfma<<<512, 512, 0, stream>>>(qbf, Kpad, VpadT, kmg, vmgt, obf);
  gemm_out_strip<<<512, 256, 0, stream>>>(obf, WoT, out_b, F, out);
}